// Round 4
// baseline (117.933 us; speedup 1.0000x reference)
//
#include <hip/hip_runtime.h>

// Problem constants (fixed by setup_inputs): V=8192, F=256, B=32, L=64.
#define V_SIZE    8192
#define F_SIZE    256
#define B_SIZE    32
#define L_SIZE    64
#define NPAIR     2016            // B*(L-1)
#define NPAIR_PAD 2048
#define NCHUNK    64              // vocab chunks of 128 (grid.y of main)
#define ESTRIDE   512             // shorts per [c] step in packed layout (64 lanes * 8)

// Math: nll = B*ln(V) + sum_pairs [ w0*(g(p) - g(tgt)) + ln(S_pair) ],
//   g(v)   = sum_f wf[f]*feat[v,f]*sign_f,  sign_f = 2*feat[prev,f]-1
//   S_pair = sum_v exp(w0*(g(v) - g(p)))    (g(p) is the EXACT max for wf>=0)
// GEMM: C = signs[2048x256] @ featw[8192x256]^T via v_mfma_f32_32x32x16_bf16.
// Packed operand layout [rowblk32][c][lane64][8]; B-tile staged ONCE per block
// into LDS (shared by 4 waves) to kill the 4x-redundant L2 streaming that held
// R2/R3 main at ~45 us. Wave tile 64 pairs x 128 cols.

typedef __attribute__((ext_vector_type(8)))  short  short8;   // 8 bf16 = 4 VGPR
typedef __attribute__((ext_vector_type(16))) float  floatx16; // 32x32 acc

__device__ __forceinline__ unsigned short f2bf(float x) {
    union { float f; unsigned u; } c; c.f = x;
    unsigned u = c.u + 0x7FFF + ((c.u >> 16) & 1);   // RNE
    return (unsigned short)(u >> 16);
}

// -------- K1: combined prep (featw pack | signs pack + gp | zero out) -------
// blocks [0,1024): fpack; blocks [1024,1536): spack+gp (4 pairs/block).
__global__ __launch_bounds__(256) void prep_kernel(
    const float* __restrict__ weights,
    const int*   __restrict__ features,
    const int*   __restrict__ seq,
    unsigned short* __restrict__ fpack,
    unsigned short* __restrict__ spack,
    float*       __restrict__ gp,
    float*       __restrict__ out) {
    const int blk = blockIdx.x, tid = threadIdx.x;
    if (blk == 0 && tid == 0) out[0] = 0.0f;   // final_kernel atomics need 0
    if (blk < 1024) {
        int gid  = blk * 256 + tid;            // 0 .. V*F/8-1
        int rb   = gid >> 10;                  // 32-row block
        int rem  = gid & 1023;
        int c    = rem >> 6;                   // K chunk (16 elems)
        int lane = rem & 63;
        int row  = rb * 32 + (lane & 31);
        int f0   = c * 16 + (lane >> 5) * 8;
        const int* src = features + row * F_SIZE + f0;
        int4 q0 = *(const int4*)(src);
        int4 q1 = *(const int4*)(src + 4);
        unsigned short r[8];
        r[0] = f2bf(weights[1 + f0 + 0] * (float)q0.x);
        r[1] = f2bf(weights[1 + f0 + 1] * (float)q0.y);
        r[2] = f2bf(weights[1 + f0 + 2] * (float)q0.z);
        r[3] = f2bf(weights[1 + f0 + 3] * (float)q0.w);
        r[4] = f2bf(weights[1 + f0 + 4] * (float)q1.x);
        r[5] = f2bf(weights[1 + f0 + 5] * (float)q1.y);
        r[6] = f2bf(weights[1 + f0 + 6] * (float)q1.z);
        r[7] = f2bf(weights[1 + f0 + 7] * (float)q1.w);
        *(uint4*)(fpack + (size_t)gid * 8) = *(const uint4*)r;
    } else {
        const int P    = (blk - 1024) * 4 + (tid >> 6);   // 0..2047
        const int lane = tid & 63;
        const int Pc   = (P < NPAIR) ? P : (NPAIR - 1);
        const int b    = Pc / 63;
        const int t    = Pc - b * 63;
        const int prev = seq[b * L_SIZE + t];
        const int f    = lane * 4;
        int4 q = *(const int4*)(features + prev * F_SIZE + f);
        unsigned short s[4];
        s[0] = q.x ? 0x3F80 : 0xBF80;          // +1 / -1 bf16
        s[1] = q.y ? 0x3F80 : 0xBF80;
        s[2] = q.z ? 0x3F80 : 0xBF80;
        s[3] = q.w ? 0x3F80 : 0xBF80;
        const int pb = P >> 5;
        const int c  = f >> 4;
        const int lp = (P & 31) + 32 * ((f >> 3) & 1);
        *(ushort4*)(spack + ((size_t)(pb * 16 + c) * 64 + lp) * 8 + (f & 7)) = *(const ushort4*)s;
        float g = weights[1 + f + 0] * (float)q.x + weights[1 + f + 1] * (float)q.y
                + weights[1 + f + 2] * (float)q.z + weights[1 + f + 3] * (float)q.w;
#pragma unroll
        for (int off = 32; off > 0; off >>= 1) g += __shfl_down(g, off);
        if (lane == 0) gp[P] = g;
    }
}

// -------- K2: main MFMA GEMM + fused exp/partial-sum ------------------------
// grid (8, 64), block 256 (4 waves), 2 blocks/CU (64 KB LDS each).
// Block: pairs [bx*256, +256), cols [by*128, +128). Wave: 64 pairs x 128 cols.
__global__ __launch_bounds__(256, 2) void main_kernel(
    const float* __restrict__ weights,
    const unsigned short* __restrict__ spack,
    const unsigned short* __restrict__ fpack,
    const float* __restrict__ gp,
    float*       __restrict__ S2) {       // [NPAIR_PAD][NCHUNK]
    __shared__ unsigned short Bs[64 * ESTRIDE];   // 64 KB: [tc*16+c][lane][8]
    const int tid  = threadIdx.x;
    const int wave = tid >> 6;
    const int lane = tid & 63;
    const int l31  = lane & 31;
    const int h    = lane >> 5;

    // Stage the block's B tile (128 cols x 256 K) once; 16 chunks per wave.
    {
        const unsigned short* src = fpack + ((size_t)((blockIdx.y * 64 + wave * 16)) * 64 + lane) * 8;
        unsigned short* dst = Bs + (wave * 16) * ESTRIDE + lane * 8;
#pragma unroll
        for (int i = 0; i < 16; ++i)
            *(uint4*)(dst + i * ESTRIDE) = *(const uint4*)(src + (size_t)i * ESTRIDE);
    }
    __syncthreads();

    const int pb0 = (blockIdx.x * 4 + wave) * 2;          // two 32-pair blocks
    const unsigned short* a0p = spack + ((size_t)(pb0 * 16) * 64 + lane) * 8;
    const unsigned short* a1p = a0p + (size_t)16 * ESTRIDE;

    floatx16 acc[2][4];
#pragma unroll
    for (int tp = 0; tp < 2; ++tp)
#pragma unroll
        for (int tc = 0; tc < 4; ++tc)
#pragma unroll
            for (int r = 0; r < 16; ++r) acc[tp][tc][r] = 0.0f;

#pragma unroll 4
    for (int c = 0; c < 16; ++c) {        // K chunks of 16
        short8 a0 = *(const short8*)(a0p + c * ESTRIDE);
        short8 a1 = *(const short8*)(a1p + c * ESTRIDE);
#pragma unroll
        for (int tc = 0; tc < 4; ++tc) {
            short8 bf = *(const short8*)(Bs + (tc * 16 + c) * ESTRIDE + lane * 8);
            acc[0][tc] = __builtin_amdgcn_mfma_f32_32x32x16_bf16(a0, bf, acc[0][tc], 0, 0, 0);
            acc[1][tc] = __builtin_amdgcn_mfma_f32_32x32x16_bf16(a1, bf, acc[1][tc], 0, 0, 0);
        }
    }

    // Epilogue: exp2(w0*log2e*(C - gp)); sum this wave's 128 cols per pair.
    const float kexp = weights[0] * 1.44269504088896340736f;
    const int Pbase = pb0 * 32;
#pragma unroll
    for (int tp = 0; tp < 2; ++tp) {
#pragma unroll
        for (int r = 0; r < 16; ++r) {
            const int P = Pbase + tp * 32 + ((r & 3) + 8 * (r >> 2) + 4 * h);
            const float gv = gp[P];
            float part = 0.0f;
#pragma unroll
            for (int tc = 0; tc < 4; ++tc)
                part += exp2f((acc[tp][tc][r] - gv) * kexp);
#pragma unroll
            for (int off = 16; off > 0; off >>= 1) part += __shfl_xor(part, off);
            if (l31 == 0) S2[(size_t)P * NCHUNK + blockIdx.y] = part;
        }
    }
}

// -------- K3: wave-per-pair nll reduction -----------------------------------
__global__ __launch_bounds__(256) void final_kernel(
    const float* __restrict__ weights,
    const int*   __restrict__ features,
    const int*   __restrict__ seq,
    const float* __restrict__ S2,
    float*       __restrict__ out) {
    const int tid  = threadIdx.x;
    const int P    = blockIdx.x * 4 + (tid >> 6);    // 0..2015 exactly
    const int lane = tid & 63;
    const int b    = P / 63;
    const int t    = P - b * 63;
    const int prev = seq[b * L_SIZE + t];
    const int tg   = seq[b * L_SIZE + t + 1];

    const int f = lane * 4;
    int4 qp = *(const int4*)(features + prev * F_SIZE + f);
    int4 qt = *(const int4*)(features + tg   * F_SIZE + f);
    float w0v = weights[1 + f + 0], w1v = weights[1 + f + 1];
    float w2v = weights[1 + f + 2], w3v = weights[1 + f + 3];
    float gpp = w0v * (float)qp.x + w1v * (float)qp.y + w2v * (float)qp.z + w3v * (float)qp.w;
    float xtp = w0v * (float)qt.x * (float)(2 * qp.x - 1)
              + w1v * (float)qt.y * (float)(2 * qp.y - 1)
              + w2v * (float)qt.z * (float)(2 * qp.z - 1)
              + w3v * (float)qt.w * (float)(2 * qp.w - 1);
    float sp = S2[(size_t)P * NCHUNK + lane];        // coalesced 256B/wave

    float a = gpp, x = xtp, s = sp;
#pragma unroll
    for (int off = 32; off > 0; off >>= 1) {
        a += __shfl_down(a, off);
        x += __shfl_down(x, off);
        s += __shfl_down(s, off);
    }
    if (lane == 0) {
        float nll = weights[0] * (a - x) + logf(s);
        atomicAdd(out, nll);
    }
    if (blockIdx.x == 0 && tid == 0)
        atomicAdd(out, (float)B_SIZE * logf((float)V_SIZE));  // nll_first
}

extern "C" void kernel_launch(void* const* d_in, const int* in_sizes, int n_in,
                              void* d_out, int out_size, void* d_ws, size_t ws_size,
                              hipStream_t stream) {
    const float* weights  = (const float*)d_in[0];   // 257
    const int*   features = (const int*)d_in[1];     // V*F ints {0,1}
    const int*   seq      = (const int*)d_in[2];     // B*L
    float* out = (float*)d_out;

    char* ws = (char*)d_ws;
    unsigned short* fpack = (unsigned short*)ws;                             // 4 MB
    unsigned short* spack = (unsigned short*)(ws + (size_t)4 * 1024 * 1024); // 1 MB
    float*          gp    = (float*)(ws + (size_t)5 * 1024 * 1024);          // 8 KB
    float*          S2    = (float*)(ws + (size_t)5 * 1024 * 1024 + 16384);  // 512 KB

    prep_kernel<<<1536, 256, 0, stream>>>(weights, features, seq, fpack, spack, gp, out);
    main_kernel<<<dim3(8, 64), 256, 0, stream>>>(weights, spack, fpack, gp, S2);
    final_kernel<<<NPAIR / 4, 256, 0, stream>>>(weights, features, seq, S2, out);
}